// Round 15
// baseline (56.751 us; speedup 1.0000x reference)
//
#include <hip/hip_runtime.h>
#include <math.h>

// SparseMultiheadAttention B=2,H=16,S=2048,DH=64, STRIDE=128, EXPR=32, bidirectional.
// Mask factorization (HW-validated rounds 0-2):
//   allowed(i,c) = (c&127)>=96 | ((c&127)==0 && c>0) | ((c>>7)==a(i))
//   a(i) = (i>>7) - ((i&127)==0 && i>0)
// R15 = R14 with the exp2 spelling fixed: __exp2f collides with glibc math.h
// macros -> use __builtin_amdgcn_exp2f (raw v_exp_f32) with exp2f fallback.
// R14 design: (a) exp2-domain softmax, log2e folded into Q pre-scale, THR 11.5
// (log2 units); (b) wave-parity sub-segment stagger (wave w computes subsegs
// in order (w&1, 1-(w&1))) to desync the block's LDS-read/exp phase convoy.
// Structure from R13: 8-wave 512-thr blocks (128 rows, grid 512), two 64-col
// sub-segments per barrier interval computed sequentially (R11-sized per-wave
// registers); 2-ahead interval pipeline (load(I+2) -> write(I+1 from packed
// regs) -> compute(I) -> pack(I+2) -> barrier); P in registers (swapped QK^T,
// lane owns the 16x16x16 A-frag); V swz ^((d&15)<<3) (odd rows as 2xb64);
// K swz ^(c&7)<<4; LDS 64KB = 2 bufs x (K 2x8K + V 2x8K) -> 2 blocks/CU.
// Sub-segments (A = R, block rows [128R,128R+128)):
//   s0..7 : summary pairs [256s+96,+128) u [256s+224,+256)       no mask
//   s8    : local [128A, +64)                                     mask a_row==A
//   s9    : local [128A+64,+96) (32) + checkpoints {128k,k=1..15}+pad (16), nn=3
//   s10/11: special block A-1 (R > 0 only); wave 0 computes (row 128R only).
// Intervals: I = {2I, 2I+1}; nI = spec ? 6 : 5 (pairs always complete).
// Coverage verified per-row (col 128A masked in checkpoint tile, unmasked in s8;
// col 128(A-1) masked in checkpoint tile for special row, unmasked in s10).

namespace {

constexpr int kS = 2048, kD = 64;

typedef __attribute__((ext_vector_type(8))) short short8;
typedef __attribute__((ext_vector_type(4))) short short4b;
typedef __attribute__((ext_vector_type(4))) float f32x4;
typedef __attribute__((ext_vector_type(4))) unsigned int u32x4;
typedef __attribute__((ext_vector_type(2))) unsigned int u32x2;

__device__ __forceinline__ float fexp2(float x) {   // raw v_exp_f32
#if __has_builtin(__builtin_amdgcn_exp2f)
    return __builtin_amdgcn_exp2f(x);
#else
    return exp2f(x);
#endif
}

__device__ __forceinline__ unsigned f2bf(float f) {           // RNE (Q only)
    unsigned u = __builtin_bit_cast(unsigned, f);
    u += 0x7fffu + ((u >> 16) & 1u);
    return u >> 16;
}
__device__ __forceinline__ unsigned pk2(float a, float b) {   // RNE pair
    return f2bf(a) | (f2bf(b) << 16);
}
__device__ __forceinline__ unsigned pkt(float a, float b) {   // truncating pair: 1 v_perm
    return __builtin_amdgcn_perm(__builtin_bit_cast(unsigned, b),
                                 __builtin_bit_cast(unsigned, a), 0x07060302u);
}

#if __has_builtin(__builtin_amdgcn_mfma_f32_16x16x16bf16_1k)
__device__ __forceinline__ f32x4 mfma16(short4b a, short4b b, f32x4 c) {
    return __builtin_amdgcn_mfma_f32_16x16x16bf16_1k(a, b, c, 0, 0, 0);
}
#else
__device__ __forceinline__ f32x4 mfma16(short4b a, short4b b, f32x4 c) {
    asm volatile("v_mfma_f32_16x16x16_bf16 %0, %1, %2, %0"
                 : "+v"(c) : "v"(a), "v"(b));
    return c;
}
#endif

__device__ __forceinline__ int seglen(int s) { return s == 9 ? 48 : (s == 11 ? 32 : 64); }

__device__ __forceinline__ int colOf(int s, int p, int A) {
    if (s < 8)  return 256 * s + (p < 32 ? 96 + p : 192 + p);
    if (s == 8) return 128 * A + p;
    if (s == 9) {
        if (p < 32) return 128 * A + 64 + p;
        const int k = p - 31;                 // 1..16
        return k < 16 ? 128 * k : 2047;       // p=47 pad (always masked)
    }
    if (s == 10) return 128 * (A - 1) + p;
    return 128 * (A - 1) + 64 + p;            // s==11
}
__device__ __forceinline__ bool maskOf(int s, int p, int a_row, int A) {
    if (s < 8)  return true;
    if (s == 8) return a_row == A;
    if (s == 9) return p < 32 ? (a_row == A) : (p < 47 && a_row != (p - 31));
    return a_row == A - 1;                    // s==10/11
}

__global__ __launch_bounds__(512) void sparse_attn13(
    const float* __restrict__ Q, const float* __restrict__ K,
    const float* __restrict__ V, float* __restrict__ Out)
{
    // buf b at b*32768: K sub-seg u at +u*8192 (swz ^(c&7)<<4),
    //                   V sub-seg u at +16384+u*8192 (swz ^((d&15)<<3))
    __shared__ __align__(16) unsigned char lds[65536];

    const int tid = threadIdx.x;
    const int wv = tid >> 6;                     // 0..7
    const int l = tid & 63, g = l >> 4, lm = l & 15;
    const int bh = blockIdx.x >> 4, R = blockIdx.x & 15;
    const int A = R;
    const int rowbase = R * 128 + wv * 16;       // wave owns 16 rows
    const bool spec = (R > 0);
    const int nsub = spec ? 12 : 10;
    const int nI   = spec ? 6 : 5;               // pairs always complete

    const float* Qb = Q + (size_t)bh * kS * kD;
    const float* Kb = K + (size_t)bh * kS * kD;
    const float* Vb = V + (size_t)bh * kS * kD;

    // Q fragment (mfma B-operand in swapped QK: col=q=lm, k=d=g*8+j+32kk)
    // pre-scale = (1/8) * log2(e): scores land directly in exp2 domain
    constexpr float kQScale = 0.125f * 1.4426950408889634f;
    short8 qa[2];
#pragma unroll
    for (int kk = 0; kk < 2; ++kk) {
        const float* qp = Qb + (size_t)(rowbase + lm) * kD + kk*32 + g*8;
        float4 a = *(const float4*)qp;
        float4 b = *(const float4*)(qp + 4);
        u32x4 t;
        t.x = pk2(a.x*kQScale, a.y*kQScale);
        t.y = pk2(a.z*kQScale, a.w*kQScale);
        t.z = pk2(b.x*kQScale, b.y*kQScale);
        t.w = pk2(b.z*kQScale, b.w*kQScale);
        qa[kk] = __builtin_bit_cast(short8, t);
    }

    // a-value for this lane's q-row (q = rowbase + lm)
    const int qrow = rowbase + lm;
    const int aq = (qrow >> 7) - (((qrow & 127) == 0 && qrow > 0) ? 1 : 0);

    float mrun = -1e30f, lpar = 0.f;   // softmax state (log2 domain) for q = lm
    f32x4 o[4];                         // O[q=4g+i][d=lm+16nv]
#pragma unroll
    for (int nv = 0; nv < 4; ++nv) o[nv] = (f32x4){0.f,0.f,0.f,0.f};

    // staging: thread-group (tid>>8) owns sub-seg u = group of each interval
    const int group = tid >> 8;                  // 0 or 1
    const int tid_g = tid & 255;
    const int kc  = tid_g >> 2,  kq4 = tid_g & 3;
    const int vc0 = (tid_g >> 5) * 8, vd0 = (tid_g & 31) * 2;

    float4 kreg[4];                      // fp32 in flight (intra-interval)
    float2 vreg[8];
    u32x4  kp0, kp1;                     // packed bf16, held ACROSS the barrier
    u32x4  vp0;
    u32x2  vp1a, vp1b;

    auto stage_load = [&](int I) {       // issue global loads only
        const int s = 2*I + group;
        if (s >= nsub) return;
        const int len = seglen(s);
        if (kc < len) {
            const float* kp = Kb + (size_t)colOf(s, kc, A) * kD + kq4*16;
            kreg[0] = *(const float4*)(kp);
            kreg[1] = *(const float4*)(kp + 4);
            kreg[2] = *(const float4*)(kp + 8);
            kreg[3] = *(const float4*)(kp + 12);
        }
        if (vc0 < len) {
#pragma unroll
            for (int j = 0; j < 8; ++j)
                vreg[j] = *(const float2*)(Vb + (size_t)colOf(s, vc0 + j, A) * kD + vd0);
        }
    };

    auto stage_pack = [&](int I) {       // vmcnt waits land here (covered by compute)
        const int s = 2*I + group;
        if (s >= nsub) return;
        const int len = seglen(s);
        if (kc < len) {
            kp0.x = pkt(kreg[0].x,kreg[0].y); kp0.y = pkt(kreg[0].z,kreg[0].w);
            kp0.z = pkt(kreg[1].x,kreg[1].y); kp0.w = pkt(kreg[1].z,kreg[1].w);
            kp1.x = pkt(kreg[2].x,kreg[2].y); kp1.y = pkt(kreg[2].z,kreg[2].w);
            kp1.z = pkt(kreg[3].x,kreg[3].y); kp1.w = pkt(kreg[3].z,kreg[3].w);
        }
        if (vc0 < len) {
            vp0.x = pkt(vreg[0].x,vreg[1].x); vp0.y = pkt(vreg[2].x,vreg[3].x);
            vp0.z = pkt(vreg[4].x,vreg[5].x); vp0.w = pkt(vreg[6].x,vreg[7].x);
            vp1a.x = pkt(vreg[0].y,vreg[1].y); vp1a.y = pkt(vreg[2].y,vreg[3].y);
            vp1b.x = pkt(vreg[4].y,vreg[5].y); vp1b.y = pkt(vreg[6].y,vreg[7].y);
        }
    };

    auto stage_write = [&](int I, int buf) {   // LDS writes from packed regs only
        const int s = 2*I + group;
        if (s >= nsub) return;
        unsigned char* ksb = lds + buf * 32768 + group * 8192;
        unsigned char* vsb = lds + buf * 32768 + 16384 + group * 8192;
        const int len = seglen(s);
        if (kc < len) {
            const unsigned b  = (unsigned)(kc*128 + kq4*32);
            const unsigned sw = ((unsigned)(kc & 7)) << 4;
            *(u32x4*)(ksb + (b ^ sw))        = kp0;
            *(u32x4*)(ksb + ((b ^ sw) ^ 16)) = kp1;
        }
        if (vc0 < len) {
            // even row vd0: swz multiple of 16 -> contiguous b128 is exact
            const unsigned swe = ((unsigned)(vd0 & 15)) << 3;
            *(u32x4*)(vsb + ((unsigned)(vd0*128 + vc0*2) ^ swe)) = vp0;
            // odd row vd0+1: swz has bit 3 -> two b64 chunks (XOR exact at 8B)
            const unsigned swo = ((unsigned)((vd0 + 1) & 15)) << 3;
            *(u32x2*)(vsb + ((unsigned)((vd0+1)*128 + vc0*2)     ^ swo)) = vp1a;
            *(u32x2*)(vsb + ((unsigned)((vd0+1)*128 + vc0*2 + 8) ^ swo)) = vp1b;
        }
    };

    const int ufirst = wv & 1;           // wave-parity stagger (desync phases)

    auto compute = [&](int I, int buf) {
        // two sub-segments, wave-parity order; per-sub-seg state dies between
#pragma unroll
        for (int uu = 0; uu < 2; ++uu) {
            const int u = uu ^ ufirst;
            const int s = 2*I + u;
            if (s >= nsub) continue;
            if (s >= 10 && wv != 0) continue;    // special: only wave 0's rows
            const int nn = (s == 9) ? 3 : ((s == 11) ? 2 : 4);
            const unsigned char* ksb = lds + buf * 32768 + u * 8192;
            const unsigned char* vsb = lds + buf * 32768 + 16384 + u * 8192;

            // S^T tiles: sf[n][i] = S[q=lm][c = 16n + 4g + i]  (log2 domain)
            f32x4 sf[4];
#pragma unroll
            for (int n = 0; n < 4; ++n) sf[n] = (f32x4){0.f,0.f,0.f,0.f};

            __builtin_amdgcn_s_setprio(1);
#pragma unroll
            for (int n = 0; n < 4; ++n) if (n < nn) {
                const int c = lm + 16*n;         // K-fragment row (A-operand)
#pragma unroll
                for (int kk = 0; kk < 2; ++kk) {
                    const unsigned byte = (unsigned)(c*128 + kk*64 + g*16) ^ (((unsigned)(c & 7)) << 4);
                    const short8 kf = *(const short8*)(ksb + byte);
                    sf[n] = __builtin_amdgcn_mfma_f32_16x16x32_bf16(kf, qa[kk], sf[n], 0, 0, 0);
                }
            }
            __builtin_amdgcn_s_setprio(0);

            if (s >= 8) {                        // mask: per lane, q-row = lm
#pragma unroll
                for (int n = 0; n < 4; ++n) if (n < nn) {
#pragma unroll
                    for (int i = 0; i < 4; ++i) {
                        const int c = 16*n + g*4 + i;
                        if (!maskOf(s, c, aq, A)) sf[n][i] = -1e30f;
                    }
                }
            }

            // row max: in-lane tree + 2 cross-g shfls; defer-max (THR=11.5 log2)
            float t = -1e30f;
#pragma unroll
            for (int n = 0; n < 4; ++n) if (n < nn) {
                t = fmaxf(t, fmaxf(fmaxf(sf[n][0], sf[n][1]), fmaxf(sf[n][2], sf[n][3])));
            }
            t = fmaxf(t, __shfl_xor(t, 16));
            t = fmaxf(t, __shfl_xor(t, 32));
            const bool need = t > mrun + 11.5f;
            if (__any(need)) {
                const float nm = fmaxf(mrun, t);
                const float al = fexp2(mrun - nm);
                mrun = nm; lpar *= al;
#pragma unroll
                for (int i = 0; i < 4; ++i) {    // redistribute al to C-layout rows
                    const float ali = __shfl(al, (g*4 + i) + 16*g);
#pragma unroll
                    for (int nv = 0; nv < 4; ++nv) o[nv][i] *= ali;
                }
            }

            // exp2 + pack: pa[n] IS the 16x16x16 A-frag (row=q=lm, k=4g+i)
            u32x2 pa[4];
            float psum = 0.f;
#pragma unroll
            for (int n = 0; n < 4; ++n) if (n < nn) {
                const float p0 = fexp2(sf[n][0] - mrun);
                const float p1 = fexp2(sf[n][1] - mrun);
                const float p2 = fexp2(sf[n][2] - mrun);
                const float p3 = fexp2(sf[n][3] - mrun);
                psum += (p0 + p1) + (p2 + p3);
                pa[n].x = pkt(p0, p1);
                pa[n].y = pkt(p2, p3);
            }
            lpar += psum;

            // PV: o[nv] += P_n * V_n, K=16 per tile; V b64 reads conflict-free
            __builtin_amdgcn_s_setprio(1);
#pragma unroll
            for (int nv = 0; nv < 4; ++nv) {
                const int d = lm + 16*nv;
                const unsigned dsw = ((unsigned)(d & 15)) << 3;
#pragma unroll
                for (int n = 0; n < 4; ++n) if (n < nn) {
                    const unsigned byte = ((unsigned)(d*128 + 32*n + 8*g)) ^ dsw;
                    const short4b vb = *(const short4b*)(vsb + byte);
                    o[nv] = mfma16(__builtin_bit_cast(short4b, pa[n]), vb, o[nv]);
                }
            }
            __builtin_amdgcn_s_setprio(0);
        }
    };

    // prologue: interval 0 fully staged; interval 1 loaded+packed (in regs)
    stage_load(0); stage_pack(0); stage_write(0, 0);
    stage_load(1); stage_pack(1);
    __syncthreads();

    for (int I = 0; I < nI; ++I) {
        if (I + 2 < nI) stage_load(I + 2);                // issue 2 ahead
        if (I + 1 < nI) stage_write(I + 1, (I + 1) & 1);  // from packed regs
        compute(I, I & 1);                                // covers load latency
        if (I + 2 < nI) stage_pack(I + 2);                // vmcnt wait ~free here
        __syncthreads();
    }

    // epilogue: total row sum for q=lm, redistribute 1/l to C-layout rows, store
    float v = lpar;
    v += __shfl_xor(v, 16);
    v += __shfl_xor(v, 32);
    const float linv = 1.f / v;
#pragma unroll
    for (int i = 0; i < 4; ++i) {
        const float inv = __shfl(linv, (g*4 + i) + 16*g);
        float* op = Out + ((size_t)bh * kS + rowbase + g*4 + i) * kD + lm;
#pragma unroll
        for (int nv = 0; nv < 4; ++nv)
            op[16*nv] = o[nv][i] * inv;
    }
}

} // namespace

extern "C" void kernel_launch(void* const* d_in, const int* in_sizes, int n_in,
                              void* d_out, int out_size, void* d_ws, size_t ws_size,
                              hipStream_t stream) {
    const float* q = (const float*)d_in[0];
    const float* k = (const float*)d_in[1];
    const float* v = (const float*)d_in[2];
    // d_in[3] (mask) is a pure function of (S,STRIDE,EXPR) reproduced in-kernel.
    float* out = (float*)d_out;
    dim3 grid(512), block(512);
    hipLaunchKernelGGL(sparse_attn13, grid, block, 0, stream, q, k, v, out);
}

// Round 16
// 49.838 us; speedup vs baseline: 1.1387x; 1.1387x over previous
//
#include <hip/hip_runtime.h>
#include <math.h>

// SparseMultiheadAttention B=2,H=16,S=2048,DH=64, STRIDE=128, EXPR=32, bidirectional.
// Mask factorization (HW-validated rounds 0-2):
//   allowed(i,c) = (c&127)>=96 | ((c&127)==0 && c>0) | ((c>>7)==a(i))
//   a(i) = (i>>7) - ((i&127)==0 && i>0)
// R16 = R13 + exp2-domain softmax ONLY (single-variable A/B after R15's
// bundled regression): log2e folded into Q pre-scale, fexp2 = raw v_exp_f32
// (__builtin_amdgcn_exp2f; '__exp2f' collides with glibc macros), THR=11.5
// log2-units. R15's wave-parity stagger REVERTED: it made LDS buffer bases
// runtime-dependent and cost ~10% (49.6 -> 56.8 us).
// Structure from R13: 8-wave 512-thr blocks (128 rows, grid 512), two 64-col
// sub-segments per barrier interval computed sequentially in STATIC order
// (compile-time LDS offsets); 2-ahead interval pipeline (load(I+2) ->
// write(I+1 from packed regs) -> compute(I) -> pack(I+2) -> barrier);
// P in registers (swapped QK^T, lane owns the 16x16x16 A-frag);
// V swz ^((d&15)<<3) (odd rows as 2xb64); K swz ^(c&7)<<4;
// LDS 64KB = 2 bufs x (K 2x8K + V 2x8K) -> 2 blocks/CU.
// Sub-segments (A = R, block rows [128R,128R+128)):
//   s0..7 : summary pairs [256s+96,+128) u [256s+224,+256)       no mask
//   s8    : local [128A, +64)                                     mask a_row==A
//   s9    : local [128A+64,+96) (32) + checkpoints {128k,k=1..15}+pad (16), nn=3
//   s10/11: special block A-1 (R > 0 only); wave 0 computes (row 128R only).
// Intervals: I = {2I, 2I+1}; nI = spec ? 6 : 5 (pairs always complete).
// Coverage verified per-row (col 128A masked in checkpoint tile, unmasked in s8;
// col 128(A-1) masked in checkpoint tile for special row, unmasked in s10).

namespace {

constexpr int kS = 2048, kD = 64;

typedef __attribute__((ext_vector_type(8))) short short8;
typedef __attribute__((ext_vector_type(4))) short short4b;
typedef __attribute__((ext_vector_type(4))) float f32x4;
typedef __attribute__((ext_vector_type(4))) unsigned int u32x4;
typedef __attribute__((ext_vector_type(2))) unsigned int u32x2;

__device__ __forceinline__ float fexp2(float x) {   // raw v_exp_f32
#if __has_builtin(__builtin_amdgcn_exp2f)
    return __builtin_amdgcn_exp2f(x);
#else
    return exp2f(x);
#endif
}

__device__ __forceinline__ unsigned f2bf(float f) {           // RNE (Q only)
    unsigned u = __builtin_bit_cast(unsigned, f);
    u += 0x7fffu + ((u >> 16) & 1u);
    return u >> 16;
}
__device__ __forceinline__ unsigned pk2(float a, float b) {   // RNE pair
    return f2bf(a) | (f2bf(b) << 16);
}
__device__ __forceinline__ unsigned pkt(float a, float b) {   // truncating pair: 1 v_perm
    return __builtin_amdgcn_perm(__builtin_bit_cast(unsigned, b),
                                 __builtin_bit_cast(unsigned, a), 0x07060302u);
}

#if __has_builtin(__builtin_amdgcn_mfma_f32_16x16x16bf16_1k)
__device__ __forceinline__ f32x4 mfma16(short4b a, short4b b, f32x4 c) {
    return __builtin_amdgcn_mfma_f32_16x16x16bf16_1k(a, b, c, 0, 0, 0);
}
#else
__device__ __forceinline__ f32x4 mfma16(short4b a, short4b b, f32x4 c) {
    asm volatile("v_mfma_f32_16x16x16_bf16 %0, %1, %2, %0"
                 : "+v"(c) : "v"(a), "v"(b));
    return c;
}
#endif

__device__ __forceinline__ int seglen(int s) { return s == 9 ? 48 : (s == 11 ? 32 : 64); }

__device__ __forceinline__ int colOf(int s, int p, int A) {
    if (s < 8)  return 256 * s + (p < 32 ? 96 + p : 192 + p);
    if (s == 8) return 128 * A + p;
    if (s == 9) {
        if (p < 32) return 128 * A + 64 + p;
        const int k = p - 31;                 // 1..16
        return k < 16 ? 128 * k : 2047;       // p=47 pad (always masked)
    }
    if (s == 10) return 128 * (A - 1) + p;
    return 128 * (A - 1) + 64 + p;            // s==11
}
__device__ __forceinline__ bool maskOf(int s, int p, int a_row, int A) {
    if (s < 8)  return true;
    if (s == 8) return a_row == A;
    if (s == 9) return p < 32 ? (a_row == A) : (p < 47 && a_row != (p - 31));
    return a_row == A - 1;                    // s==10/11
}

__global__ __launch_bounds__(512) void sparse_attn14(
    const float* __restrict__ Q, const float* __restrict__ K,
    const float* __restrict__ V, float* __restrict__ Out)
{
    // buf b at b*32768: K sub-seg u at +u*8192 (swz ^(c&7)<<4),
    //                   V sub-seg u at +16384+u*8192 (swz ^((d&15)<<3))
    __shared__ __align__(16) unsigned char lds[65536];

    const int tid = threadIdx.x;
    const int wv = tid >> 6;                     // 0..7
    const int l = tid & 63, g = l >> 4, lm = l & 15;
    const int bh = blockIdx.x >> 4, R = blockIdx.x & 15;
    const int A = R;
    const int rowbase = R * 128 + wv * 16;       // wave owns 16 rows
    const bool spec = (R > 0);
    const int nsub = spec ? 12 : 10;
    const int nI   = spec ? 6 : 5;               // pairs always complete

    const float* Qb = Q + (size_t)bh * kS * kD;
    const float* Kb = K + (size_t)bh * kS * kD;
    const float* Vb = V + (size_t)bh * kS * kD;

    // Q fragment (mfma B-operand in swapped QK: col=q=lm, k=d=g*8+j+32kk)
    // pre-scale = (1/8) * log2(e): scores land directly in exp2 domain
    constexpr float kQScale = 0.125f * 1.4426950408889634f;
    short8 qa[2];
#pragma unroll
    for (int kk = 0; kk < 2; ++kk) {
        const float* qp = Qb + (size_t)(rowbase + lm) * kD + kk*32 + g*8;
        float4 a = *(const float4*)qp;
        float4 b = *(const float4*)(qp + 4);
        u32x4 t;
        t.x = pk2(a.x*kQScale, a.y*kQScale);
        t.y = pk2(a.z*kQScale, a.w*kQScale);
        t.z = pk2(b.x*kQScale, b.y*kQScale);
        t.w = pk2(b.z*kQScale, b.w*kQScale);
        qa[kk] = __builtin_bit_cast(short8, t);
    }

    // a-value for this lane's q-row (q = rowbase + lm)
    const int qrow = rowbase + lm;
    const int aq = (qrow >> 7) - (((qrow & 127) == 0 && qrow > 0) ? 1 : 0);

    float mrun = -1e30f, lpar = 0.f;   // softmax state (log2 domain) for q = lm
    f32x4 o[4];                         // O[q=4g+i][d=lm+16nv]
#pragma unroll
    for (int nv = 0; nv < 4; ++nv) o[nv] = (f32x4){0.f,0.f,0.f,0.f};

    // staging: thread-group (tid>>8) owns sub-seg u = group of each interval
    const int group = tid >> 8;                  // 0 or 1
    const int tid_g = tid & 255;
    const int kc  = tid_g >> 2,  kq4 = tid_g & 3;
    const int vc0 = (tid_g >> 5) * 8, vd0 = (tid_g & 31) * 2;

    float4 kreg[4];                      // fp32 in flight (intra-interval)
    float2 vreg[8];
    u32x4  kp0, kp1;                     // packed bf16, held ACROSS the barrier
    u32x4  vp0;
    u32x2  vp1a, vp1b;

    auto stage_load = [&](int I) {       // issue global loads only
        const int s = 2*I + group;
        if (s >= nsub) return;
        const int len = seglen(s);
        if (kc < len) {
            const float* kp = Kb + (size_t)colOf(s, kc, A) * kD + kq4*16;
            kreg[0] = *(const float4*)(kp);
            kreg[1] = *(const float4*)(kp + 4);
            kreg[2] = *(const float4*)(kp + 8);
            kreg[3] = *(const float4*)(kp + 12);
        }
        if (vc0 < len) {
#pragma unroll
            for (int j = 0; j < 8; ++j)
                vreg[j] = *(const float2*)(Vb + (size_t)colOf(s, vc0 + j, A) * kD + vd0);
        }
    };

    auto stage_pack = [&](int I) {       // vmcnt waits land here (covered by compute)
        const int s = 2*I + group;
        if (s >= nsub) return;
        const int len = seglen(s);
        if (kc < len) {
            kp0.x = pkt(kreg[0].x,kreg[0].y); kp0.y = pkt(kreg[0].z,kreg[0].w);
            kp0.z = pkt(kreg[1].x,kreg[1].y); kp0.w = pkt(kreg[1].z,kreg[1].w);
            kp1.x = pkt(kreg[2].x,kreg[2].y); kp1.y = pkt(kreg[2].z,kreg[2].w);
            kp1.z = pkt(kreg[3].x,kreg[3].y); kp1.w = pkt(kreg[3].z,kreg[3].w);
        }
        if (vc0 < len) {
            vp0.x = pkt(vreg[0].x,vreg[1].x); vp0.y = pkt(vreg[2].x,vreg[3].x);
            vp0.z = pkt(vreg[4].x,vreg[5].x); vp0.w = pkt(vreg[6].x,vreg[7].x);
            vp1a.x = pkt(vreg[0].y,vreg[1].y); vp1a.y = pkt(vreg[2].y,vreg[3].y);
            vp1b.x = pkt(vreg[4].y,vreg[5].y); vp1b.y = pkt(vreg[6].y,vreg[7].y);
        }
    };

    auto stage_write = [&](int I, int buf) {   // LDS writes from packed regs only
        const int s = 2*I + group;
        if (s >= nsub) return;
        unsigned char* ksb = lds + buf * 32768 + group * 8192;
        unsigned char* vsb = lds + buf * 32768 + 16384 + group * 8192;
        const int len = seglen(s);
        if (kc < len) {
            const unsigned b  = (unsigned)(kc*128 + kq4*32);
            const unsigned sw = ((unsigned)(kc & 7)) << 4;
            *(u32x4*)(ksb + (b ^ sw))        = kp0;
            *(u32x4*)(ksb + ((b ^ sw) ^ 16)) = kp1;
        }
        if (vc0 < len) {
            // even row vd0: swz multiple of 16 -> contiguous b128 is exact
            const unsigned swe = ((unsigned)(vd0 & 15)) << 3;
            *(u32x4*)(vsb + ((unsigned)(vd0*128 + vc0*2) ^ swe)) = vp0;
            // odd row vd0+1: swz has bit 3 -> two b64 chunks (XOR exact at 8B)
            const unsigned swo = ((unsigned)((vd0 + 1) & 15)) << 3;
            *(u32x2*)(vsb + ((unsigned)((vd0+1)*128 + vc0*2)     ^ swo)) = vp1a;
            *(u32x2*)(vsb + ((unsigned)((vd0+1)*128 + vc0*2 + 8) ^ swo)) = vp1b;
        }
    };

    auto compute = [&](int I, int buf) {
        // two sub-segments back-to-back (static order -> compile-time offsets);
        // per-sub-seg state dies between (keeps live VGPRs at R11 levels)
#pragma unroll
        for (int u = 0; u < 2; ++u) {
            const int s = 2*I + u;
            if (s >= nsub) continue;
            if (s >= 10 && wv != 0) continue;    // special: only wave 0's rows
            const int nn = (s == 9) ? 3 : ((s == 11) ? 2 : 4);
            const unsigned char* ksb = lds + buf * 32768 + u * 8192;
            const unsigned char* vsb = lds + buf * 32768 + 16384 + u * 8192;

            // S^T tiles: sf[n][i] = S[q=lm][c = 16n + 4g + i]  (log2 domain)
            f32x4 sf[4];
#pragma unroll
            for (int n = 0; n < 4; ++n) sf[n] = (f32x4){0.f,0.f,0.f,0.f};

            __builtin_amdgcn_s_setprio(1);
#pragma unroll
            for (int n = 0; n < 4; ++n) if (n < nn) {
                const int c = lm + 16*n;         // K-fragment row (A-operand)
#pragma unroll
                for (int kk = 0; kk < 2; ++kk) {
                    const unsigned byte = (unsigned)(c*128 + kk*64 + g*16) ^ (((unsigned)(c & 7)) << 4);
                    const short8 kf = *(const short8*)(ksb + byte);
                    sf[n] = __builtin_amdgcn_mfma_f32_16x16x32_bf16(kf, qa[kk], sf[n], 0, 0, 0);
                }
            }
            __builtin_amdgcn_s_setprio(0);

            if (s >= 8) {                        // mask: per lane, q-row = lm
#pragma unroll
                for (int n = 0; n < 4; ++n) if (n < nn) {
#pragma unroll
                    for (int i = 0; i < 4; ++i) {
                        const int c = 16*n + g*4 + i;
                        if (!maskOf(s, c, aq, A)) sf[n][i] = -1e30f;
                    }
                }
            }

            // row max: in-lane tree + 2 cross-g shfls; defer-max (THR=11.5 log2)
            float t = -1e30f;
#pragma unroll
            for (int n = 0; n < 4; ++n) if (n < nn) {
                t = fmaxf(t, fmaxf(fmaxf(sf[n][0], sf[n][1]), fmaxf(sf[n][2], sf[n][3])));
            }
            t = fmaxf(t, __shfl_xor(t, 16));
            t = fmaxf(t, __shfl_xor(t, 32));
            const bool need = t > mrun + 11.5f;
            if (__any(need)) {
                const float nm = fmaxf(mrun, t);
                const float al = fexp2(mrun - nm);
                mrun = nm; lpar *= al;
#pragma unroll
                for (int i = 0; i < 4; ++i) {    // redistribute al to C-layout rows
                    const float ali = __shfl(al, (g*4 + i) + 16*g);
#pragma unroll
                    for (int nv = 0; nv < 4; ++nv) o[nv][i] *= ali;
                }
            }

            // exp2 + pack: pa[n] IS the 16x16x16 A-frag (row=q=lm, k=4g+i)
            u32x2 pa[4];
            float psum = 0.f;
#pragma unroll
            for (int n = 0; n < 4; ++n) if (n < nn) {
                const float p0 = fexp2(sf[n][0] - mrun);
                const float p1 = fexp2(sf[n][1] - mrun);
                const float p2 = fexp2(sf[n][2] - mrun);
                const float p3 = fexp2(sf[n][3] - mrun);
                psum += (p0 + p1) + (p2 + p3);
                pa[n].x = pkt(p0, p1);
                pa[n].y = pkt(p2, p3);
            }
            lpar += psum;

            // PV: o[nv] += P_n * V_n, K=16 per tile; V b64 reads conflict-free
            __builtin_amdgcn_s_setprio(1);
#pragma unroll
            for (int nv = 0; nv < 4; ++nv) {
                const int d = lm + 16*nv;
                const unsigned dsw = ((unsigned)(d & 15)) << 3;
#pragma unroll
                for (int n = 0; n < 4; ++n) if (n < nn) {
                    const unsigned byte = ((unsigned)(d*128 + 32*n + 8*g)) ^ dsw;
                    const short4b vb = *(const short4b*)(vsb + byte);
                    o[nv] = mfma16(__builtin_bit_cast(short4b, pa[n]), vb, o[nv]);
                }
            }
            __builtin_amdgcn_s_setprio(0);
        }
    };

    // prologue: interval 0 fully staged; interval 1 loaded+packed (in regs)
    stage_load(0); stage_pack(0); stage_write(0, 0);
    stage_load(1); stage_pack(1);
    __syncthreads();

    for (int I = 0; I < nI; ++I) {
        if (I + 2 < nI) stage_load(I + 2);                // issue 2 ahead
        if (I + 1 < nI) stage_write(I + 1, (I + 1) & 1);  // from packed regs
        compute(I, I & 1);                                // covers load latency
        if (I + 2 < nI) stage_pack(I + 2);                // vmcnt wait ~free here
        __syncthreads();
    }

    // epilogue: total row sum for q=lm, redistribute 1/l to C-layout rows, store
    float v = lpar;
    v += __shfl_xor(v, 16);
    v += __shfl_xor(v, 32);
    const float linv = 1.f / v;
#pragma unroll
    for (int i = 0; i < 4; ++i) {
        const float inv = __shfl(linv, (g*4 + i) + 16*g);
        float* op = Out + ((size_t)bh * kS + rowbase + g*4 + i) * kD + lm;
#pragma unroll
        for (int nv = 0; nv < 4; ++nv)
            op[16*nv] = o[nv][i] * inv;
    }
}

} // namespace

extern "C" void kernel_launch(void* const* d_in, const int* in_sizes, int n_in,
                              void* d_out, int out_size, void* d_ws, size_t ws_size,
                              hipStream_t stream) {
    const float* q = (const float*)d_in[0];
    const float* k = (const float*)d_in[1];
    const float* v = (const float*)d_in[2];
    // d_in[3] (mask) is a pure function of (S,STRIDE,EXPR) reproduced in-kernel.
    float* out = (float*)d_out;
    dim3 grid(512), block(512);
    hipLaunchKernelGGL(sparse_attn14, grid, block, 0, stream, q, k, v, out);
}

// Round 17
// 48.009 us; speedup vs baseline: 1.1821x; 1.0381x over previous
//
#include <hip/hip_runtime.h>
#include <math.h>

// SparseMultiheadAttention B=2,H=16,S=2048,DH=64, STRIDE=128, EXPR=32, bidirectional.
// Mask factorization (HW-validated rounds 0-2):
//   allowed(i,c) = (c&127)>=96 | ((c&127)==0 && c>0) | ((c>>7)==a(i))
//   a(i) = (i>>7) - ((i&127)==0 && i>0)
// R17 = R16 + branch-free fast path for intervals 0..3 (s=0..7: summary segs,
// nn=4, no mask, both subsegs always present) with the two subsegments' QK
// MFMA/LDS chains HAND-INTERLEAVED (independent chains fill each other's
// latency; sf0+sf1 live = +16 VGPR, target <=128). SM0->PV0->SM1->PV1 in one
// straight-line block (SM1's max tree can hoist into PV0's MFMA shadow).
// I=4 (s=8,9: masks, nn=3) and I=5 (spec s=10,11, wave-0 only) keep the
// generic guarded path. Numeric order identical to R16.
// Structure: 8-wave 512-thr blocks (128 rows, grid 512); 2 subsegs/interval;
// 2-ahead pipeline (load(I+2) -> write(I+1 from packed regs) -> compute(I) ->
// pack(I+2) -> barrier); exp2-domain softmax (log2e in Q pre-scale, THR 11.5);
// P in registers (swapped QK^T -> lane owns the 16x16x16 A-frag);
// V swz ^((d&15)<<3) (odd rows as 2xb64); K swz ^(c&7)<<4;
// LDS 64KB = 2 bufs x (K 2x8K + V 2x8K) -> 2 blocks/CU.
// Sub-segments (A = R, block rows [128R,128R+128)):
//   s0..7 : summary pairs [256s+96,+128) u [256s+224,+256)       no mask
//   s8    : local [128A, +64)                                     mask a_row==A
//   s9    : local [128A+64,+96) (32) + checkpoints {128k,k=1..15}+pad (16), nn=3
//   s10/11: special block A-1 (R > 0 only); wave 0 computes (row 128R only).
// Intervals: I = {2I, 2I+1}; nI = spec ? 6 : 5 (pairs always complete).
// Coverage verified per-row (col 128A masked in checkpoint tile, unmasked in s8;
// col 128(A-1) masked in checkpoint tile for special row, unmasked in s10).

namespace {

constexpr int kS = 2048, kD = 64;

typedef __attribute__((ext_vector_type(8))) short short8;
typedef __attribute__((ext_vector_type(4))) short short4b;
typedef __attribute__((ext_vector_type(4))) float f32x4;
typedef __attribute__((ext_vector_type(4))) unsigned int u32x4;
typedef __attribute__((ext_vector_type(2))) unsigned int u32x2;

__device__ __forceinline__ float fexp2(float x) {   // raw v_exp_f32
#if __has_builtin(__builtin_amdgcn_exp2f)
    return __builtin_amdgcn_exp2f(x);
#else
    return exp2f(x);
#endif
}

__device__ __forceinline__ unsigned f2bf(float f) {           // RNE (Q only)
    unsigned u = __builtin_bit_cast(unsigned, f);
    u += 0x7fffu + ((u >> 16) & 1u);
    return u >> 16;
}
__device__ __forceinline__ unsigned pk2(float a, float b) {   // RNE pair
    return f2bf(a) | (f2bf(b) << 16);
}
__device__ __forceinline__ unsigned pkt(float a, float b) {   // truncating pair: 1 v_perm
    return __builtin_amdgcn_perm(__builtin_bit_cast(unsigned, b),
                                 __builtin_bit_cast(unsigned, a), 0x07060302u);
}

__device__ __forceinline__ f32x4 mfma32(short8 a, short8 b, f32x4 c) {
    return __builtin_amdgcn_mfma_f32_16x16x32_bf16(a, b, c, 0, 0, 0);
}
#if __has_builtin(__builtin_amdgcn_mfma_f32_16x16x16bf16_1k)
__device__ __forceinline__ f32x4 mfma16(short4b a, short4b b, f32x4 c) {
    return __builtin_amdgcn_mfma_f32_16x16x16bf16_1k(a, b, c, 0, 0, 0);
}
#else
__device__ __forceinline__ f32x4 mfma16(short4b a, short4b b, f32x4 c) {
    asm volatile("v_mfma_f32_16x16x16_bf16 %0, %1, %2, %0"
                 : "+v"(c) : "v"(a), "v"(b));
    return c;
}
#endif

__device__ __forceinline__ int seglen(int s) { return s == 9 ? 48 : (s == 11 ? 32 : 64); }

__device__ __forceinline__ int colOf(int s, int p, int A) {
    if (s < 8)  return 256 * s + (p < 32 ? 96 + p : 192 + p);
    if (s == 8) return 128 * A + p;
    if (s == 9) {
        if (p < 32) return 128 * A + 64 + p;
        const int k = p - 31;                 // 1..16
        return k < 16 ? 128 * k : 2047;       // p=47 pad (always masked)
    }
    if (s == 10) return 128 * (A - 1) + p;
    return 128 * (A - 1) + 64 + p;            // s==11
}
__device__ __forceinline__ bool maskOf(int s, int p, int a_row, int A) {
    if (s < 8)  return true;
    if (s == 8) return a_row == A;
    if (s == 9) return p < 32 ? (a_row == A) : (p < 47 && a_row != (p - 31));
    return a_row == A - 1;                    // s==10/11
}

__global__ __launch_bounds__(512) void sparse_attn15(
    const float* __restrict__ Q, const float* __restrict__ K,
    const float* __restrict__ V, float* __restrict__ Out)
{
    // buf b at b*32768: K sub-seg u at +u*8192 (swz ^(c&7)<<4),
    //                   V sub-seg u at +16384+u*8192 (swz ^((d&15)<<3))
    __shared__ __align__(16) unsigned char lds[65536];

    const int tid = threadIdx.x;
    const int wv = tid >> 6;                     // 0..7
    const int l = tid & 63, g = l >> 4, lm = l & 15;
    const int bh = blockIdx.x >> 4, R = blockIdx.x & 15;
    const int A = R;
    const int rowbase = R * 128 + wv * 16;       // wave owns 16 rows
    const bool spec = (R > 0);
    const int nsub = spec ? 12 : 10;
    const int nI   = spec ? 6 : 5;               // pairs always complete

    const float* Qb = Q + (size_t)bh * kS * kD;
    const float* Kb = K + (size_t)bh * kS * kD;
    const float* Vb = V + (size_t)bh * kS * kD;

    // Q fragment (mfma B-operand in swapped QK: col=q=lm, k=d=g*8+j+32kk)
    // pre-scale = (1/8) * log2(e): scores land directly in exp2 domain
    constexpr float kQScale = 0.125f * 1.4426950408889634f;
    short8 qa[2];
#pragma unroll
    for (int kk = 0; kk < 2; ++kk) {
        const float* qp = Qb + (size_t)(rowbase + lm) * kD + kk*32 + g*8;
        float4 a = *(const float4*)qp;
        float4 b = *(const float4*)(qp + 4);
        u32x4 t;
        t.x = pk2(a.x*kQScale, a.y*kQScale);
        t.y = pk2(a.z*kQScale, a.w*kQScale);
        t.z = pk2(b.x*kQScale, b.y*kQScale);
        t.w = pk2(b.z*kQScale, b.w*kQScale);
        qa[kk] = __builtin_bit_cast(short8, t);
    }

    // a-value for this lane's q-row (q = rowbase + lm)
    const int qrow = rowbase + lm;
    const int aq = (qrow >> 7) - (((qrow & 127) == 0 && qrow > 0) ? 1 : 0);

    float mrun = -1e30f, lpar = 0.f;   // softmax state (log2 domain) for q = lm
    f32x4 o[4];                         // O[q=4g+i][d=lm+16nv]
#pragma unroll
    for (int nv = 0; nv < 4; ++nv) o[nv] = (f32x4){0.f,0.f,0.f,0.f};

    // staging: thread-group (tid>>8) owns sub-seg u = group of each interval
    const int group = tid >> 8;                  // 0 or 1
    const int tid_g = tid & 255;
    const int kc  = tid_g >> 2,  kq4 = tid_g & 3;
    const int vc0 = (tid_g >> 5) * 8, vd0 = (tid_g & 31) * 2;

    float4 kreg[4];                      // fp32 in flight (intra-interval)
    float2 vreg[8];
    u32x4  kp0, kp1;                     // packed bf16, held ACROSS the barrier
    u32x4  vp0;
    u32x2  vp1a, vp1b;

    auto stage_load = [&](int I) {       // issue global loads only
        const int s = 2*I + group;
        if (s >= nsub) return;
        const int len = seglen(s);
        if (kc < len) {
            const float* kp = Kb + (size_t)colOf(s, kc, A) * kD + kq4*16;
            kreg[0] = *(const float4*)(kp);
            kreg[1] = *(const float4*)(kp + 4);
            kreg[2] = *(const float4*)(kp + 8);
            kreg[3] = *(const float4*)(kp + 12);
        }
        if (vc0 < len) {
#pragma unroll
            for (int j = 0; j < 8; ++j)
                vreg[j] = *(const float2*)(Vb + (size_t)colOf(s, vc0 + j, A) * kD + vd0);
        }
    };

    auto stage_pack = [&](int I) {       // vmcnt waits land here (covered by compute)
        const int s = 2*I + group;
        if (s >= nsub) return;
        const int len = seglen(s);
        if (kc < len) {
            kp0.x = pkt(kreg[0].x,kreg[0].y); kp0.y = pkt(kreg[0].z,kreg[0].w);
            kp0.z = pkt(kreg[1].x,kreg[1].y); kp0.w = pkt(kreg[1].z,kreg[1].w);
            kp1.x = pkt(kreg[2].x,kreg[2].y); kp1.y = pkt(kreg[2].z,kreg[2].w);
            kp1.z = pkt(kreg[3].x,kreg[3].y); kp1.w = pkt(kreg[3].z,kreg[3].w);
        }
        if (vc0 < len) {
            vp0.x = pkt(vreg[0].x,vreg[1].x); vp0.y = pkt(vreg[2].x,vreg[3].x);
            vp0.z = pkt(vreg[4].x,vreg[5].x); vp0.w = pkt(vreg[6].x,vreg[7].x);
            vp1a.x = pkt(vreg[0].y,vreg[1].y); vp1a.y = pkt(vreg[2].y,vreg[3].y);
            vp1b.x = pkt(vreg[4].y,vreg[5].y); vp1b.y = pkt(vreg[6].y,vreg[7].y);
        }
    };

    auto stage_write = [&](int I, int buf) {   // LDS writes from packed regs only
        const int s = 2*I + group;
        if (s >= nsub) return;
        unsigned char* ksb = lds + buf * 32768 + group * 8192;
        unsigned char* vsb = lds + buf * 32768 + 16384 + group * 8192;
        const int len = seglen(s);
        if (kc < len) {
            const unsigned b  = (unsigned)(kc*128 + kq4*32);
            const unsigned sw = ((unsigned)(kc & 7)) << 4;
            *(u32x4*)(ksb + (b ^ sw))        = kp0;
            *(u32x4*)(ksb + ((b ^ sw) ^ 16)) = kp1;
        }
        if (vc0 < len) {
            // even row vd0: swz multiple of 16 -> contiguous b128 is exact
            const unsigned swe = ((unsigned)(vd0 & 15)) << 3;
            *(u32x4*)(vsb + ((unsigned)(vd0*128 + vc0*2) ^ swe)) = vp0;
            // odd row vd0+1: swz has bit 3 -> two b64 chunks (XOR exact at 8B)
            const unsigned swo = ((unsigned)((vd0 + 1) & 15)) << 3;
            *(u32x2*)(vsb + ((unsigned)((vd0+1)*128 + vc0*2)     ^ swo)) = vp1a;
            *(u32x2*)(vsb + ((unsigned)((vd0+1)*128 + vc0*2 + 8) ^ swo)) = vp1b;
        }
    };

    // --- softmax + PV for one subsegment, P from sf in registers ------------
    auto sm_pv = [&](f32x4 (&sf)[4], const unsigned char* vsb, int nn) {
        float t = -1e30f;
#pragma unroll
        for (int n = 0; n < 4; ++n) if (n < nn) {
            t = fmaxf(t, fmaxf(fmaxf(sf[n][0], sf[n][1]), fmaxf(sf[n][2], sf[n][3])));
        }
        t = fmaxf(t, __shfl_xor(t, 16));
        t = fmaxf(t, __shfl_xor(t, 32));
        const bool need = t > mrun + 11.5f;
        if (__any(need)) {
            const float nm = fmaxf(mrun, t);
            const float al = fexp2(mrun - nm);
            mrun = nm; lpar *= al;
#pragma unroll
            for (int i = 0; i < 4; ++i) {    // redistribute al to C-layout rows
                const float ali = __shfl(al, (g*4 + i) + 16*g);
#pragma unroll
                for (int nv = 0; nv < 4; ++nv) o[nv][i] *= ali;
            }
        }
        u32x2 pa[4];
        float psum = 0.f;
#pragma unroll
        for (int n = 0; n < 4; ++n) if (n < nn) {
            const float p0 = fexp2(sf[n][0] - mrun);
            const float p1 = fexp2(sf[n][1] - mrun);
            const float p2 = fexp2(sf[n][2] - mrun);
            const float p3 = fexp2(sf[n][3] - mrun);
            psum += (p0 + p1) + (p2 + p3);
            pa[n].x = pkt(p0, p1);
            pa[n].y = pkt(p2, p3);
        }
        lpar += psum;
        __builtin_amdgcn_s_setprio(1);
#pragma unroll
        for (int nv = 0; nv < 4; ++nv) {
            const int d = lm + 16*nv;
            const unsigned dsw = ((unsigned)(d & 15)) << 3;
#pragma unroll
            for (int n = 0; n < 4; ++n) if (n < nn) {
                const unsigned byte = ((unsigned)(d*128 + 32*n + 8*g)) ^ dsw;
                const short4b vb = *(const short4b*)(vsb + byte);
                o[nv] = mfma16(__builtin_bit_cast(short4b, pa[n]), vb, o[nv]);
            }
        }
        __builtin_amdgcn_s_setprio(0);
    };

    // --- fast path: I=0..3 (s=0..7), branch-free, QK of both subsegs mixed --
    auto compute_fast = [&](int buf) {
        const unsigned char* base = lds + buf * 32768;
        const unsigned char* ksb0 = base;
        const unsigned char* ksb1 = base + 8192;
        const unsigned char* vsb0 = base + 16384;
        const unsigned char* vsb1 = base + 24576;

        f32x4 sf0[4], sf1[4];
#pragma unroll
        for (int n = 0; n < 4; ++n) {
            sf0[n] = (f32x4){0.f,0.f,0.f,0.f};
            sf1[n] = (f32x4){0.f,0.f,0.f,0.f};
        }
        __builtin_amdgcn_s_setprio(1);
#pragma unroll
        for (int n = 0; n < 4; ++n) {
            const int c = lm + 16*n;
#pragma unroll
            for (int kk = 0; kk < 2; ++kk) {
                const unsigned byte = (unsigned)(c*128 + kk*64 + g*16) ^ (((unsigned)(c & 7)) << 4);
                const short8 kf0 = *(const short8*)(ksb0 + byte);
                const short8 kf1 = *(const short8*)(ksb1 + byte);
                sf0[n] = mfma32(kf0, qa[kk], sf0[n]);
                sf1[n] = mfma32(kf1, qa[kk], sf1[n]);
            }
        }
        __builtin_amdgcn_s_setprio(0);
        sm_pv(sf0, vsb0, 4);
        sm_pv(sf1, vsb1, 4);
    };

    // --- generic path: I>=4 (masked / special subsegs) ----------------------
    auto compute_gen = [&](int I, int buf) {
#pragma unroll
        for (int u = 0; u < 2; ++u) {
            const int s = 2*I + u;
            if (s >= nsub) continue;
            if (s >= 10 && wv != 0) continue;    // special: only wave 0's rows
            const int nn = (s == 9) ? 3 : ((s == 11) ? 2 : 4);
            const unsigned char* ksb = lds + buf * 32768 + u * 8192;
            const unsigned char* vsb = lds + buf * 32768 + 16384 + u * 8192;

            f32x4 sf[4];
#pragma unroll
            for (int n = 0; n < 4; ++n) sf[n] = (f32x4){0.f,0.f,0.f,0.f};

            __builtin_amdgcn_s_setprio(1);
#pragma unroll
            for (int n = 0; n < 4; ++n) if (n < nn) {
                const int c = lm + 16*n;
#pragma unroll
                for (int kk = 0; kk < 2; ++kk) {
                    const unsigned byte = (unsigned)(c*128 + kk*64 + g*16) ^ (((unsigned)(c & 7)) << 4);
                    const short8 kf = *(const short8*)(ksb + byte);
                    sf[n] = mfma32(kf, qa[kk], sf[n]);
                }
            }
            __builtin_amdgcn_s_setprio(0);

            // mask: per lane, q-row = lm
#pragma unroll
            for (int n = 0; n < 4; ++n) if (n < nn) {
#pragma unroll
                for (int i = 0; i < 4; ++i) {
                    const int c = 16*n + g*4 + i;
                    if (!maskOf(s, c, aq, A)) sf[n][i] = -1e30f;
                }
            }
            sm_pv(sf, vsb, nn);
        }
    };

    // prologue: interval 0 fully staged; interval 1 loaded+packed (in regs)
    stage_load(0); stage_pack(0); stage_write(0, 0);
    stage_load(1); stage_pack(1);
    __syncthreads();

    for (int I = 0; I < nI; ++I) {
        if (I + 2 < nI) stage_load(I + 2);                // issue 2 ahead
        if (I + 1 < nI) stage_write(I + 1, (I + 1) & 1);  // from packed regs
        if (I < 4) compute_fast(I & 1);                   // covers load latency
        else       compute_gen(I, I & 1);
        if (I + 2 < nI) stage_pack(I + 2);                // vmcnt wait ~free here
        __syncthreads();
    }

    // epilogue: total row sum for q=lm, redistribute 1/l to C-layout rows, store
    float v = lpar;
    v += __shfl_xor(v, 16);
    v += __shfl_xor(v, 32);
    const float linv = 1.f / v;
#pragma unroll
    for (int i = 0; i < 4; ++i) {
        const float inv = __shfl(linv, (g*4 + i) + 16*g);
        float* op = Out + ((size_t)bh * kS + rowbase + g*4 + i) * kD + lm;
#pragma unroll
        for (int nv = 0; nv < 4; ++nv)
            op[16*nv] = o[nv][i] * inv;
    }
}

} // namespace

extern "C" void kernel_launch(void* const* d_in, const int* in_sizes, int n_in,
                              void* d_out, int out_size, void* d_ws, size_t ws_size,
                              hipStream_t stream) {
    const float* q = (const float*)d_in[0];
    const float* k = (const float*)d_in[1];
    const float* v = (const float*)d_in[2];
    // d_in[3] (mask) is a pure function of (S,STRIDE,EXPR) reproduced in-kernel.
    float* out = (float*)d_out;
    dim3 grid(512), block(512);
    hipLaunchKernelGGL(sparse_attn15, grid, block, 0, stream, q, k, v, out);
}

// Round 18
// 47.078 us; speedup vs baseline: 1.2055x; 1.0198x over previous
//
#include <hip/hip_runtime.h>
#include <math.h>

// SparseMultiheadAttention B=2,H=16,S=2048,DH=64, STRIDE=128, EXPR=32, bidirectional.
// Mask factorization (HW-validated rounds 0-2):
//   allowed(i,c) = (c&127)>=96 | ((c&127)==0 && c>0) | ((c>>7)==a(i))
//   a(i) = (i>>7) - ((i&127)==0 && i>0)
// R18 = R17 + (a) JOINT softmax across the interval's two subsegments in the
// fast path (one max/shfl/rescale per 128-col tile instead of two); (b) T14
// interval reorder: load(I+2) -> compute(I) -> write(I+1) -> pack(I+2) ->
// barrier (ds_writes no longer queue ahead of compute's first ds_reads).
// Structure: 8-wave 512-thr blocks (128 rows, grid 512); 2 subsegs/interval;
// exp2-domain softmax (log2e in Q pre-scale, THR 11.5); P in registers
// (swapped QK^T -> lane owns the 16x16x16 A-frag); fast path I<4 branch-free
// with QK chains of both subsegs interleaved; V swz ^((d&15)<<3) (odd rows as
// 2xb64); K swz ^(c&7)<<4; LDS 64KB = 2 bufs x (K 2x8K + V 2x8K) -> 2 blk/CU.
// Sub-segments (A = R, block rows [128R,128R+128)):
//   s0..7 : summary pairs [256s+96,+128) u [256s+224,+256)       no mask
//   s8    : local [128A, +64)                                     mask a_row==A
//   s9    : local [128A+64,+96) (32) + checkpoints {128k,k=1..15}+pad (16), nn=3
//   s10/11: special block A-1 (R > 0 only); wave 0 computes (row 128R only).
// Intervals: I = {2I, 2I+1}; nI = spec ? 6 : 5 (pairs always complete).
// Coverage verified per-row (col 128A masked in checkpoint tile, unmasked in s8;
// col 128(A-1) masked in checkpoint tile for special row, unmasked in s10).

namespace {

constexpr int kS = 2048, kD = 64;

typedef __attribute__((ext_vector_type(8))) short short8;
typedef __attribute__((ext_vector_type(4))) short short4b;
typedef __attribute__((ext_vector_type(4))) float f32x4;
typedef __attribute__((ext_vector_type(4))) unsigned int u32x4;
typedef __attribute__((ext_vector_type(2))) unsigned int u32x2;

__device__ __forceinline__ float fexp2(float x) {   // raw v_exp_f32
#if __has_builtin(__builtin_amdgcn_exp2f)
    return __builtin_amdgcn_exp2f(x);
#else
    return exp2f(x);
#endif
}

__device__ __forceinline__ unsigned f2bf(float f) {           // RNE (Q only)
    unsigned u = __builtin_bit_cast(unsigned, f);
    u += 0x7fffu + ((u >> 16) & 1u);
    return u >> 16;
}
__device__ __forceinline__ unsigned pk2(float a, float b) {   // RNE pair
    return f2bf(a) | (f2bf(b) << 16);
}
__device__ __forceinline__ unsigned pkt(float a, float b) {   // truncating pair: 1 v_perm
    return __builtin_amdgcn_perm(__builtin_bit_cast(unsigned, b),
                                 __builtin_bit_cast(unsigned, a), 0x07060302u);
}

__device__ __forceinline__ f32x4 mfma32(short8 a, short8 b, f32x4 c) {
    return __builtin_amdgcn_mfma_f32_16x16x32_bf16(a, b, c, 0, 0, 0);
}
#if __has_builtin(__builtin_amdgcn_mfma_f32_16x16x16bf16_1k)
__device__ __forceinline__ f32x4 mfma16(short4b a, short4b b, f32x4 c) {
    return __builtin_amdgcn_mfma_f32_16x16x16bf16_1k(a, b, c, 0, 0, 0);
}
#else
__device__ __forceinline__ f32x4 mfma16(short4b a, short4b b, f32x4 c) {
    asm volatile("v_mfma_f32_16x16x16_bf16 %0, %1, %2, %0"
                 : "+v"(c) : "v"(a), "v"(b));
    return c;
}
#endif

__device__ __forceinline__ int seglen(int s) { return s == 9 ? 48 : (s == 11 ? 32 : 64); }

__device__ __forceinline__ int colOf(int s, int p, int A) {
    if (s < 8)  return 256 * s + (p < 32 ? 96 + p : 192 + p);
    if (s == 8) return 128 * A + p;
    if (s == 9) {
        if (p < 32) return 128 * A + 64 + p;
        const int k = p - 31;                 // 1..16
        return k < 16 ? 128 * k : 2047;       // p=47 pad (always masked)
    }
    if (s == 10) return 128 * (A - 1) + p;
    return 128 * (A - 1) + 64 + p;            // s==11
}
__device__ __forceinline__ bool maskOf(int s, int p, int a_row, int A) {
    if (s < 8)  return true;
    if (s == 8) return a_row == A;
    if (s == 9) return p < 32 ? (a_row == A) : (p < 47 && a_row != (p - 31));
    return a_row == A - 1;                    // s==10/11
}

__global__ __launch_bounds__(512) void sparse_attn16(
    const float* __restrict__ Q, const float* __restrict__ K,
    const float* __restrict__ V, float* __restrict__ Out)
{
    // buf b at b*32768: K sub-seg u at +u*8192 (swz ^(c&7)<<4),
    //                   V sub-seg u at +16384+u*8192 (swz ^((d&15)<<3))
    __shared__ __align__(16) unsigned char lds[65536];

    const int tid = threadIdx.x;
    const int wv = tid >> 6;                     // 0..7
    const int l = tid & 63, g = l >> 4, lm = l & 15;
    const int bh = blockIdx.x >> 4, R = blockIdx.x & 15;
    const int A = R;
    const int rowbase = R * 128 + wv * 16;       // wave owns 16 rows
    const bool spec = (R > 0);
    const int nsub = spec ? 12 : 10;
    const int nI   = spec ? 6 : 5;               // pairs always complete

    const float* Qb = Q + (size_t)bh * kS * kD;
    const float* Kb = K + (size_t)bh * kS * kD;
    const float* Vb = V + (size_t)bh * kS * kD;

    // Q fragment (mfma B-operand in swapped QK: col=q=lm, k=d=g*8+j+32kk)
    // pre-scale = (1/8) * log2(e): scores land directly in exp2 domain
    constexpr float kQScale = 0.125f * 1.4426950408889634f;
    short8 qa[2];
#pragma unroll
    for (int kk = 0; kk < 2; ++kk) {
        const float* qp = Qb + (size_t)(rowbase + lm) * kD + kk*32 + g*8;
        float4 a = *(const float4*)qp;
        float4 b = *(const float4*)(qp + 4);
        u32x4 t;
        t.x = pk2(a.x*kQScale, a.y*kQScale);
        t.y = pk2(a.z*kQScale, a.w*kQScale);
        t.z = pk2(b.x*kQScale, b.y*kQScale);
        t.w = pk2(b.z*kQScale, b.w*kQScale);
        qa[kk] = __builtin_bit_cast(short8, t);
    }

    // a-value for this lane's q-row (q = rowbase + lm)
    const int qrow = rowbase + lm;
    const int aq = (qrow >> 7) - (((qrow & 127) == 0 && qrow > 0) ? 1 : 0);

    float mrun = -1e30f, lpar = 0.f;   // softmax state (log2 domain) for q = lm
    f32x4 o[4];                         // O[q=4g+i][d=lm+16nv]
#pragma unroll
    for (int nv = 0; nv < 4; ++nv) o[nv] = (f32x4){0.f,0.f,0.f,0.f};

    // staging: thread-group (tid>>8) owns sub-seg u = group of each interval
    const int group = tid >> 8;                  // 0 or 1
    const int tid_g = tid & 255;
    const int kc  = tid_g >> 2,  kq4 = tid_g & 3;
    const int vc0 = (tid_g >> 5) * 8, vd0 = (tid_g & 31) * 2;

    float4 kreg[4];                      // fp32 in flight (intra-interval)
    float2 vreg[8];
    u32x4  kp0, kp1;                     // packed bf16, held ACROSS the barrier
    u32x4  vp0;
    u32x2  vp1a, vp1b;

    auto stage_load = [&](int I) {       // issue global loads only
        const int s = 2*I + group;
        if (s >= nsub) return;
        const int len = seglen(s);
        if (kc < len) {
            const float* kp = Kb + (size_t)colOf(s, kc, A) * kD + kq4*16;
            kreg[0] = *(const float4*)(kp);
            kreg[1] = *(const float4*)(kp + 4);
            kreg[2] = *(const float4*)(kp + 8);
            kreg[3] = *(const float4*)(kp + 12);
        }
        if (vc0 < len) {
#pragma unroll
            for (int j = 0; j < 8; ++j)
                vreg[j] = *(const float2*)(Vb + (size_t)colOf(s, vc0 + j, A) * kD + vd0);
        }
    };

    auto stage_pack = [&](int I) {       // vmcnt waits land here (covered by compute)
        const int s = 2*I + group;
        if (s >= nsub) return;
        const int len = seglen(s);
        if (kc < len) {
            kp0.x = pkt(kreg[0].x,kreg[0].y); kp0.y = pkt(kreg[0].z,kreg[0].w);
            kp0.z = pkt(kreg[1].x,kreg[1].y); kp0.w = pkt(kreg[1].z,kreg[1].w);
            kp1.x = pkt(kreg[2].x,kreg[2].y); kp1.y = pkt(kreg[2].z,kreg[2].w);
            kp1.z = pkt(kreg[3].x,kreg[3].y); kp1.w = pkt(kreg[3].z,kreg[3].w);
        }
        if (vc0 < len) {
            vp0.x = pkt(vreg[0].x,vreg[1].x); vp0.y = pkt(vreg[2].x,vreg[3].x);
            vp0.z = pkt(vreg[4].x,vreg[5].x); vp0.w = pkt(vreg[6].x,vreg[7].x);
            vp1a.x = pkt(vreg[0].y,vreg[1].y); vp1a.y = pkt(vreg[2].y,vreg[3].y);
            vp1b.x = pkt(vreg[4].y,vreg[5].y); vp1b.y = pkt(vreg[6].y,vreg[7].y);
        }
    };

    auto stage_write = [&](int I, int buf) {   // LDS writes from packed regs only
        const int s = 2*I + group;
        if (s >= nsub) return;
        unsigned char* ksb = lds + buf * 32768 + group * 8192;
        unsigned char* vsb = lds + buf * 32768 + 16384 + group * 8192;
        const int len = seglen(s);
        if (kc < len) {
            const unsigned b  = (unsigned)(kc*128 + kq4*32);
            const unsigned sw = ((unsigned)(kc & 7)) << 4;
            *(u32x4*)(ksb + (b ^ sw))        = kp0;
            *(u32x4*)(ksb + ((b ^ sw) ^ 16)) = kp1;
        }
        if (vc0 < len) {
            // even row vd0: swz multiple of 16 -> contiguous b128 is exact
            const unsigned swe = ((unsigned)(vd0 & 15)) << 3;
            *(u32x4*)(vsb + ((unsigned)(vd0*128 + vc0*2) ^ swe)) = vp0;
            // odd row vd0+1: swz has bit 3 -> two b64 chunks (XOR exact at 8B)
            const unsigned swo = ((unsigned)((vd0 + 1) & 15)) << 3;
            *(u32x2*)(vsb + ((unsigned)((vd0+1)*128 + vc0*2)     ^ swo)) = vp1a;
            *(u32x2*)(vsb + ((unsigned)((vd0+1)*128 + vc0*2 + 8) ^ swo)) = vp1b;
        }
    };

    // --- exp2+pack+PV for one subsegment (assumes mrun already current) -----
    auto exp_pv = [&](f32x4 (&sf)[4], const unsigned char* vsb, int nn) {
        u32x2 pa[4];
        float psum = 0.f;
#pragma unroll
        for (int n = 0; n < 4; ++n) if (n < nn) {
            const float p0 = fexp2(sf[n][0] - mrun);
            const float p1 = fexp2(sf[n][1] - mrun);
            const float p2 = fexp2(sf[n][2] - mrun);
            const float p3 = fexp2(sf[n][3] - mrun);
            psum += (p0 + p1) + (p2 + p3);
            pa[n].x = pkt(p0, p1);
            pa[n].y = pkt(p2, p3);
        }
        lpar += psum;
        __builtin_amdgcn_s_setprio(1);
#pragma unroll
        for (int nv = 0; nv < 4; ++nv) {
            const int d = lm + 16*nv;
            const unsigned dsw = ((unsigned)(d & 15)) << 3;
#pragma unroll
            for (int n = 0; n < 4; ++n) if (n < nn) {
                const unsigned byte = ((unsigned)(d*128 + 32*n + 8*g)) ^ dsw;
                const short4b vb = *(const short4b*)(vsb + byte);
                o[nv] = mfma16(__builtin_bit_cast(short4b, pa[n]), vb, o[nv]);
            }
        }
        __builtin_amdgcn_s_setprio(0);
    };

    // rescale helper: update mrun/lpar/o given tile max t (defer-max THR=11.5)
    auto rescale = [&](float t) {
        const bool need = t > mrun + 11.5f;
        if (__any(need)) {
            const float nm = fmaxf(mrun, t);
            const float al = fexp2(mrun - nm);
            mrun = nm; lpar *= al;
#pragma unroll
            for (int i = 0; i < 4; ++i) {    // redistribute al to C-layout rows
                const float ali = __shfl(al, (g*4 + i) + 16*g);
#pragma unroll
                for (int nv = 0; nv < 4; ++nv) o[nv][i] *= ali;
            }
        }
    };

    // --- fast path: I=0..3 (s=0..7), branch-free, QK mixed, JOINT softmax ---
    auto compute_fast = [&](int buf) {
        const unsigned char* base = lds + buf * 32768;
        const unsigned char* ksb0 = base;
        const unsigned char* ksb1 = base + 8192;
        const unsigned char* vsb0 = base + 16384;
        const unsigned char* vsb1 = base + 24576;

        f32x4 sf0[4], sf1[4];
#pragma unroll
        for (int n = 0; n < 4; ++n) {
            sf0[n] = (f32x4){0.f,0.f,0.f,0.f};
            sf1[n] = (f32x4){0.f,0.f,0.f,0.f};
        }
        __builtin_amdgcn_s_setprio(1);
#pragma unroll
        for (int n = 0; n < 4; ++n) {
            const int c = lm + 16*n;
#pragma unroll
            for (int kk = 0; kk < 2; ++kk) {
                const unsigned byte = (unsigned)(c*128 + kk*64 + g*16) ^ (((unsigned)(c & 7)) << 4);
                const short8 kf0 = *(const short8*)(ksb0 + byte);
                const short8 kf1 = *(const short8*)(ksb1 + byte);
                sf0[n] = mfma32(kf0, qa[kk], sf0[n]);
                sf1[n] = mfma32(kf1, qa[kk], sf1[n]);
            }
        }
        __builtin_amdgcn_s_setprio(0);

        // joint max over both subsegments (128-col tile): ONE cross-lane reduce
        float t = -1e30f;
#pragma unroll
        for (int n = 0; n < 4; ++n) {
            t = fmaxf(t, fmaxf(fmaxf(sf0[n][0], sf0[n][1]), fmaxf(sf0[n][2], sf0[n][3])));
            t = fmaxf(t, fmaxf(fmaxf(sf1[n][0], sf1[n][1]), fmaxf(sf1[n][2], sf1[n][3])));
        }
        t = fmaxf(t, __shfl_xor(t, 16));
        t = fmaxf(t, __shfl_xor(t, 32));
        rescale(t);
        exp_pv(sf0, vsb0, 4);
        exp_pv(sf1, vsb1, 4);
    };

    // --- generic path: I>=4 (masked / special subsegs) ----------------------
    auto compute_gen = [&](int I, int buf) {
#pragma unroll
        for (int u = 0; u < 2; ++u) {
            const int s = 2*I + u;
            if (s >= nsub) continue;
            if (s >= 10 && wv != 0) continue;    // special: only wave 0's rows
            const int nn = (s == 9) ? 3 : ((s == 11) ? 2 : 4);
            const unsigned char* ksb = lds + buf * 32768 + u * 8192;
            const unsigned char* vsb = lds + buf * 32768 + 16384 + u * 8192;

            f32x4 sf[4];
#pragma unroll
            for (int n = 0; n < 4; ++n) sf[n] = (f32x4){0.f,0.f,0.f,0.f};

            __builtin_amdgcn_s_setprio(1);
#pragma unroll
            for (int n = 0; n < 4; ++n) if (n < nn) {
                const int c = lm + 16*n;
#pragma unroll
                for (int kk = 0; kk < 2; ++kk) {
                    const unsigned byte = (unsigned)(c*128 + kk*64 + g*16) ^ (((unsigned)(c & 7)) << 4);
                    const short8 kf = *(const short8*)(ksb + byte);
                    sf[n] = mfma32(kf, qa[kk], sf[n]);
                }
            }
            __builtin_amdgcn_s_setprio(0);

            // mask: per lane, q-row = lm
#pragma unroll
            for (int n = 0; n < 4; ++n) if (n < nn) {
#pragma unroll
                for (int i = 0; i < 4; ++i) {
                    const int c = 16*n + g*4 + i;
                    if (!maskOf(s, c, aq, A)) sf[n][i] = -1e30f;
                }
            }

            float t = -1e30f;
#pragma unroll
            for (int n = 0; n < 4; ++n) if (n < nn) {
                t = fmaxf(t, fmaxf(fmaxf(sf[n][0], sf[n][1]), fmaxf(sf[n][2], sf[n][3])));
            }
            t = fmaxf(t, __shfl_xor(t, 16));
            t = fmaxf(t, __shfl_xor(t, 32));
            rescale(t);
            exp_pv(sf, vsb, nn);
        }
    };

    // prologue: interval 0 fully staged; interval 1 loaded+packed (in regs)
    stage_load(0); stage_pack(0); stage_write(0, 0);
    stage_load(1); stage_pack(1);
    __syncthreads();

    for (int I = 0; I < nI; ++I) {
        if (I + 2 < nI) stage_load(I + 2);                // issue 2 ahead
        if (I < 4) compute_fast(I & 1);                   // covers load latency
        else       compute_gen(I, I & 1);
        if (I + 1 < nI) stage_write(I + 1, (I + 1) & 1);  // T14: write LATE
        if (I + 2 < nI) stage_pack(I + 2);                // vmcnt wait ~free here
        __syncthreads();
    }

    // epilogue: total row sum for q=lm, redistribute 1/l to C-layout rows, store
    float v = lpar;
    v += __shfl_xor(v, 16);
    v += __shfl_xor(v, 32);
    const float linv = 1.f / v;
#pragma unroll
    for (int i = 0; i < 4; ++i) {
        const float inv = __shfl(linv, (g*4 + i) + 16*g);
        float* op = Out + ((size_t)bh * kS + rowbase + g*4 + i) * kD + lm;
#pragma unroll
        for (int nv = 0; nv < 4; ++nv)
            op[16*nv] = o[nv][i] * inv;
    }
}

} // namespace

extern "C" void kernel_launch(void* const* d_in, const int* in_sizes, int n_in,
                              void* d_out, int out_size, void* d_ws, size_t ws_size,
                              hipStream_t stream) {
    const float* q = (const float*)d_in[0];
    const float* k = (const float*)d_in[1];
    const float* v = (const float*)d_in[2];
    // d_in[3] (mask) is a pure function of (S,STRIDE,EXPR) reproduced in-kernel.
    float* out = (float*)d_out;
    dim3 grid(512), block(512);
    hipLaunchKernelGGL(sparse_attn16, grid, block, 0, stream, q, k, v, out);
}